// Round 1
// 1555.571 us; speedup vs baseline: 1.0867x; 1.0867x over previous
//
#include <hip/hip_runtime.h>

namespace {

constexpr int T     = 1024;
constexpr int HDIM  = 2880;
constexpr int DDIM  = 2880;
constexpr int NE    = 8;
constexpr int TWO_D = 5760;
constexpr float ALPHA = 1.702f;
constexpr float LIMIT = 7.0f;

// fallback-path LDS row stride
constexpr int LDSS = 40;

typedef __attribute__((ext_vector_type(8))) short bf16x8;          // MFMA A/B frag (4 VGPR)
typedef __attribute__((ext_vector_type(4))) unsigned short u16x4;  // 8B LDS store
typedef __attribute__((ext_vector_type(4))) float f32x4;           // MFMA C/D frag

__device__ __forceinline__ unsigned short f2bf(float f) {
  union { float f; unsigned u; } x; x.f = f;
  unsigned u = x.u;
  u += 0x7fffu + ((u >> 16) & 1u);   // RNE
  return (unsigned short)(u >> 16);
}

// async global->LDS, 16B per lane. LDS dest = wave-uniform base + lane*16.
__device__ __forceinline__ void async16(const void* g, void* l) {
  __builtin_amdgcn_global_load_lds(
      (const __attribute__((address_space(1))) unsigned int*)g,
      (__attribute__((address_space(3))) unsigned int*)l, 16, 0, 0);
}

} // namespace

// ===========================================================================
// FAST PATH
// ===========================================================================

// X fp32 -> bf16, streaming. grid T*H/2048, block 256.
__global__ __launch_bounds__(256) void cvt_x_kernel(const float* __restrict__ X,
                                                    unsigned short* __restrict__ Xb) {
  const int i = (blockIdx.x * 256 + threadIdx.x) * 8;
  const f32x4 a = *(const f32x4*)(X + i);
  const f32x4 b = *(const f32x4*)(X + i + 4);
  bf16x8 pv;
  pv[0] = (short)f2bf(a.x); pv[1] = (short)f2bf(a.y);
  pv[2] = (short)f2bf(a.z); pv[3] = (short)f2bf(a.w);
  pv[4] = (short)f2bf(b.x); pv[5] = (short)f2bf(b.y);
  pv[6] = (short)f2bf(b.z); pv[7] = (short)f2bf(b.w);
  *(bf16x8*)(Xb + i) = pv;
}

// src (gridDim.z, R, C) fp32  ->  dst (gridDim.z, C, R) bf16.
// 64x64 tile via LDS; pad 70 keeps phase-2 gathers at <=2-way bank conflict
// (stride 8 rows = 1120 B -> bank step 24 -> 4 banks x 2 addrs, free per m136).
__global__ __launch_bounds__(256) void transpose_cvt_kernel(
    const float* __restrict__ src, unsigned short* __restrict__ dst,
    int R, int C) {
  __shared__ __align__(16) unsigned short lt[64][70];
  const size_t eo = (size_t)blockIdx.z * R * C;
  const float* sp = src + eo;
  unsigned short* dp = dst + eo;
  const int c0 = blockIdx.x * 64;
  const int r0 = blockIdx.y * 64;
  const int t  = threadIdx.x;

  const int lr = t >> 4;          // 0..15
  const int lc = (t & 15) * 4;    // 0,4,..60  (coalesced 256B rows)
#pragma unroll
  for (int it = 0; it < 4; ++it) {
    const int rr = lr + it * 16;
    const f32x4 v = *(const f32x4*)(sp + (size_t)(r0 + rr) * C + c0 + lc);
    const unsigned w0 = (unsigned)f2bf(v.x) | ((unsigned)f2bf(v.y) << 16);
    const unsigned w1 = (unsigned)f2bf(v.z) | ((unsigned)f2bf(v.w) << 16);
    *(unsigned*)(&lt[rr][lc])     = w0;   // 4B-aligned (140*rr + 2*lc)
    *(unsigned*)(&lt[rr][lc + 2]) = w1;
  }
  __syncthreads();

  const int dr  = (t & 7) * 8;    // 8 src-rows -> one 16B dst chunk
  const int dcb = t >> 3;         // 0..31 src col (dst row); 128B global chunks
#pragma unroll
  for (int it = 0; it < 2; ++it) {
    const int c = dcb + it * 32;
    bf16x8 ov;
#pragma unroll
    for (int j = 0; j < 8; ++j) ov[j] = (short)lt[dr + j][c];
    *(bf16x8*)(dp + (size_t)(c0 + c) * R + r0 + dr) = ov;
  }
}

// GEMM1 (m97 structure): A' = act(X @ W1 + b1) * rw  -> (E,T,D) bf16.
// Operands bf16, linear LDS [128][32], global_load_lds x4 per wave per K-step.
// grid (8,45,8), block 256.
__global__ __launch_bounds__(256) void gemm1_fast(
    const unsigned short* __restrict__ Xb,   // (T,H) bf16
    const unsigned short* __restrict__ W1T,  // (E,2D,H) bf16  (pre-transposed)
    const float* __restrict__ B1,
    const float* __restrict__ RW,
    unsigned short* __restrict__ A)          // (E,T,D) bf16
{
  __shared__ __align__(16) unsigned short lA[128 * 32];
  __shared__ __align__(16) unsigned short lB[128 * 32];

  const int tid = threadIdx.x;
  const int m0 = blockIdx.x * 128;
  const int n0 = blockIdx.y * 128;
  const int e  = blockIdx.z;
  const unsigned short* Wp = W1T + (size_t)e * TWO_D * HDIM;

  f32x4 acc[4][4];
#pragma unroll
  for (int i = 0; i < 4; ++i)
#pragma unroll
    for (int j = 0; j < 4; ++j) acc[i][j] = (f32x4)0.f;

  const int w    = tid >> 6;
  const int lane = tid & 63;
  const int wm   = w & 1, wn = w >> 1;
  const int r    = lane & 15, q = lane >> 4;

  // staging: lane covers row (w*32 + it*16 + lane>>2), k-chunk (lane&3)*8
  const int srow = lane >> 2;
  const int skc  = (lane & 3) * 8;
  const unsigned short* ga = Xb + (size_t)(m0 + w * 32 + srow) * HDIM + skc;
  const unsigned short* gb = Wp + (size_t)(n0 + w * 32 + srow) * HDIM + skc;
  unsigned short* la0 = lA + (w * 2) * 512;   // wave-uniform LDS bases
  unsigned short* lb0 = lB + (w * 2) * 512;

  for (int kt = 0; kt < HDIM / 32; ++kt) {
    const int k0 = kt * 32;
    async16(ga + k0,                        la0);
    async16(ga + (size_t)16 * HDIM + k0,    la0 + 512);
    async16(gb + k0,                        lb0);
    async16(gb + (size_t)16 * HDIM + k0,    lb0 + 512);
    __syncthreads();   // compiler drains vmcnt(0) before s_barrier

    const unsigned short* pA = &lA[(wm * 64 + r) * 32 + q * 8];
    const unsigned short* pB = &lB[(wn * 64 + r) * 32 + q * 8];
    bf16x8 af[4], bfr[4];
#pragma unroll
    for (int i = 0; i < 4; ++i) af[i]  = *(const bf16x8*)(pA + i * 512);
#pragma unroll
    for (int j = 0; j < 4; ++j) bfr[j] = *(const bf16x8*)(pB + j * 512);
#pragma unroll
    for (int i = 0; i < 4; ++i)
#pragma unroll
      for (int j = 0; j < 4; ++j)
        acc[i][j] = __builtin_amdgcn_mfma_f32_16x16x32_bf16(af[i], bfr[j], acc[i][j], 0, 0, 0);

    __syncthreads();
  }

  // epilogue: bias, gate/up pairing via shfl_xor(1), activation, rw scale
  const float* bp = B1 + (size_t)e * TWO_D;
#pragma unroll
  for (int i = 0; i < 4; ++i) {
    const int mb = m0 + wm * 64 + i * 16 + q * 4;
    float rwv[4];
#pragma unroll
    for (int p = 0; p < 4; ++p) rwv[p] = RW[(mb + p) * NE + e];
#pragma unroll
    for (int j = 0; j < 4; ++j) {
      const int c = n0 + wn * 64 + j * 16 + r;
      const float bias = bp[c];
#pragma unroll
      for (int p = 0; p < 4; ++p) {
        float v = acc[i][j][p] + bias;
        float o = __shfl_xor(v, 1, 64);
        float gate = (r & 1) ? o : v;
        float up   = (r & 1) ? v : o;
        gate = fminf(gate, LIMIT);
        up   = fminf(fmaxf(up, -LIMIT), LIMIT);
        float glu = gate / (1.f + __expf(-ALPHA * gate));
        float a   = (up + 1.f) * glu * rwv[p];
        if ((r & 1) == 0) {
          int d = c >> 1;
          A[(size_t)e * T * DDIM + (size_t)(mb + p) * DDIM + d] = f2bf(a);
        }
      }
    }
  }
}

// GEMM2 (m97 structure): Yp[e] = A'[e] @ W2T[e]^T  (per-expert partial, no atomics)
// grid (8,23,8), block 256. Last n-block clamps staging rows, guards stores.
__global__ __launch_bounds__(256) void gemm2_fast(
    const unsigned short* __restrict__ A,    // (E,T,D) bf16
    const unsigned short* __restrict__ W2T,  // (E,H,D) bf16 (pre-transposed)
    float* __restrict__ Yp)                  // (E,T,H) fp32 partials
{
  __shared__ __align__(16) unsigned short lA[128 * 32];
  __shared__ __align__(16) unsigned short lB[128 * 32];

  const int tid = threadIdx.x;
  const int m0 = blockIdx.x * 128;
  const int n0 = blockIdx.y * 128;
  const int e  = blockIdx.z;
  const unsigned short* Ap = A   + (size_t)e * T * DDIM;
  const unsigned short* Wp = W2T + (size_t)e * HDIM * DDIM;

  f32x4 acc[4][4];
#pragma unroll
  for (int i = 0; i < 4; ++i)
#pragma unroll
    for (int j = 0; j < 4; ++j) acc[i][j] = (f32x4)0.f;

  const int w    = tid >> 6;
  const int lane = tid & 63;
  const int wm   = w & 1, wn = w >> 1;
  const int r    = lane & 15, q = lane >> 4;

  const int srow = lane >> 2;
  const int skc  = (lane & 3) * 8;
  int br0 = n0 + w * 32 + srow;       // B rows (h), clamp ragged tail
  int br1 = br0 + 16;
  if (br0 > HDIM - 1) br0 = HDIM - 1;
  if (br1 > HDIM - 1) br1 = HDIM - 1;
  const unsigned short* ga  = Ap + (size_t)(m0 + w * 32 + srow) * DDIM + skc;
  const unsigned short* gb0 = Wp + (size_t)br0 * DDIM + skc;
  const unsigned short* gb1 = Wp + (size_t)br1 * DDIM + skc;
  unsigned short* la0 = lA + (w * 2) * 512;
  unsigned short* lb0 = lB + (w * 2) * 512;

  for (int kt = 0; kt < DDIM / 32; ++kt) {
    const int k0 = kt * 32;
    async16(ga  + k0,                     la0);
    async16(ga  + (size_t)16 * DDIM + k0, la0 + 512);
    async16(gb0 + k0,                     lb0);
    async16(gb1 + k0,                     lb0 + 512);
    __syncthreads();

    const unsigned short* pA = &lA[(wm * 64 + r) * 32 + q * 8];
    const unsigned short* pB = &lB[(wn * 64 + r) * 32 + q * 8];
    bf16x8 af[4], bfr[4];
#pragma unroll
    for (int i = 0; i < 4; ++i) af[i]  = *(const bf16x8*)(pA + i * 512);
#pragma unroll
    for (int j = 0; j < 4; ++j) bfr[j] = *(const bf16x8*)(pB + j * 512);
#pragma unroll
    for (int i = 0; i < 4; ++i)
#pragma unroll
      for (int j = 0; j < 4; ++j)
        acc[i][j] = __builtin_amdgcn_mfma_f32_16x16x32_bf16(af[i], bfr[j], acc[i][j], 0, 0, 0);

    __syncthreads();
  }

#pragma unroll
  for (int i = 0; i < 4; ++i) {
    const int mb = m0 + wm * 64 + i * 16 + q * 4;
#pragma unroll
    for (int j = 0; j < 4; ++j) {
      const int h = n0 + wn * 64 + j * 16 + r;
      if (h < HDIM) {
#pragma unroll
        for (int p = 0; p < 4; ++p)
          Yp[((size_t)e * T + (mb + p)) * HDIM + h] = acc[i][j][p];
      }
    }
  }
}

// Y[t,h] = sum_e Yp[e,t,h] + sum_e rw[t,e]*b2[e,h].  grid T*H/1024, block 256.
__global__ __launch_bounds__(256) void reduce_bias_kernel(
    const float* __restrict__ Yp, const float* __restrict__ RW,
    const float* __restrict__ B2, float* __restrict__ Y) {
  const int idx = (blockIdx.x * 256 + threadIdx.x) * 4;
  const int t = idx / HDIM;
  const int h = idx - t * HDIM;
  f32x4 s = (f32x4)0.f;
#pragma unroll
  for (int e = 0; e < NE; ++e) {
    const f32x4 v = *(const f32x4*)(Yp + ((size_t)e * T + t) * HDIM + h);
    const f32x4 b = *(const f32x4*)(B2 + (size_t)e * HDIM + h);
    const float rw = RW[t * NE + e];
    s.x += v.x + rw * b.x;
    s.y += v.y + rw * b.y;
    s.z += v.z + rw * b.z;
    s.w += v.w + rw * b.w;
  }
  *(f32x4*)(Y + idx) = s;
}

// ===========================================================================
// FALLBACK PATH (previous verified kernels, used if workspace too small)
// ===========================================================================

__global__ void init_bias_kernel(const float* __restrict__ RW,
                                 const float* __restrict__ B2,
                                 float* __restrict__ Y) {
  int h = blockIdx.x * 64 + threadIdx.x;
  int t = blockIdx.y;
  float s = 0.f;
#pragma unroll
  for (int e = 0; e < NE; ++e) s += RW[t * NE + e] * B2[e * HDIM + h];
  Y[(size_t)t * HDIM + h] = s;
}

__global__ __launch_bounds__(256) void gemm1_act_kernel(
    const float* __restrict__ X, const float* __restrict__ W1,
    const float* __restrict__ B1, const float* __restrict__ RW,
    unsigned short* __restrict__ A) {
  __shared__ __align__(16) unsigned short lA[128 * LDSS];
  __shared__ __align__(16) unsigned short lB[128 * LDSS];
  const int tid = threadIdx.x;
  const int m0 = blockIdx.x * 128;
  const int n0 = blockIdx.y * 128;
  const int e  = blockIdx.z;
  const float* Wp = W1 + (size_t)e * HDIM * TWO_D;
  f32x4 acc[4][4];
#pragma unroll
  for (int i = 0; i < 4; ++i)
#pragma unroll
    for (int j = 0; j < 4; ++j) acc[i][j] = (f32x4)0.f;
  const int w = tid >> 6, lane = tid & 63;
  const int wm = w & 1, wn = w >> 1;
  const int r = lane & 15, q = lane >> 4;
  const int sa_m = tid >> 3, sa_q = tid & 7;
  const int sb_n = tid & 127, sb_k = tid >> 7;
  for (int kt = 0; kt < HDIM / 32; ++kt) {
    const int k0g = kt * 32;
#pragma unroll
    for (int it = 0; it < 4; ++it) {
      int m = sa_m + it * 32;
      const f32x4 v = *(const f32x4*)(X + (size_t)(m0 + m) * HDIM + k0g + sa_q * 4);
      u16x4 pv = { f2bf(v.x), f2bf(v.y), f2bf(v.z), f2bf(v.w) };
      *(u16x4*)(&lA[m * LDSS + sa_q * 4]) = pv;
    }
#pragma unroll
    for (int it = 0; it < 2; ++it) {
      int k0 = (sb_k + it * 2) * 8;
      float f[8];
#pragma unroll
      for (int rr = 0; rr < 8; ++rr)
        f[rr] = Wp[(size_t)(k0g + k0 + rr) * TWO_D + n0 + sb_n];
      bf16x8 pv = { (short)f2bf(f[0]), (short)f2bf(f[1]), (short)f2bf(f[2]), (short)f2bf(f[3]),
                    (short)f2bf(f[4]), (short)f2bf(f[5]), (short)f2bf(f[6]), (short)f2bf(f[7]) };
      *(bf16x8*)(&lB[sb_n * LDSS + k0]) = pv;
    }
    __syncthreads();
    const unsigned short* pA = &lA[(wm * 64 + r) * LDSS + q * 8];
    const unsigned short* pB = &lB[(wn * 64 + r) * LDSS + q * 8];
    bf16x8 af[4], bfr[4];
#pragma unroll
    for (int i = 0; i < 4; ++i) af[i]  = *(const bf16x8*)(pA + i * 16 * LDSS);
#pragma unroll
    for (int j = 0; j < 4; ++j) bfr[j] = *(const bf16x8*)(pB + j * 16 * LDSS);
#pragma unroll
    for (int i = 0; i < 4; ++i)
#pragma unroll
      for (int j = 0; j < 4; ++j)
        acc[i][j] = __builtin_amdgcn_mfma_f32_16x16x32_bf16(af[i], bfr[j], acc[i][j], 0, 0, 0);
    __syncthreads();
  }
  const float* bp = B1 + (size_t)e * TWO_D;
#pragma unroll
  for (int i = 0; i < 4; ++i) {
    const int mb = m0 + wm * 64 + i * 16 + q * 4;
    float rwv[4];
#pragma unroll
    for (int p = 0; p < 4; ++p) rwv[p] = RW[(mb + p) * NE + e];
#pragma unroll
    for (int j = 0; j < 4; ++j) {
      const int c = n0 + wn * 64 + j * 16 + r;
      const float bias = bp[c];
#pragma unroll
      for (int p = 0; p < 4; ++p) {
        float v = acc[i][j][p] + bias;
        float o = __shfl_xor(v, 1, 64);
        float gate = (r & 1) ? o : v;
        float up   = (r & 1) ? v : o;
        gate = fminf(gate, LIMIT);
        up   = fminf(fmaxf(up, -LIMIT), LIMIT);
        float glu = gate / (1.f + __expf(-ALPHA * gate));
        float a   = (up + 1.f) * glu * rwv[p];
        if ((r & 1) == 0) {
          int d = c >> 1;
          A[(size_t)e * T * DDIM + (size_t)(mb + p) * DDIM + d] = f2bf(a);
        }
      }
    }
  }
}

__global__ __launch_bounds__(256) void gemm2_acc_kernel(
    const unsigned short* __restrict__ A, const float* __restrict__ W2,
    float* __restrict__ Y) {
  __shared__ __align__(16) unsigned short lA[128 * LDSS];
  __shared__ __align__(16) unsigned short lB[128 * LDSS];
  const int tid = threadIdx.x;
  const int m0 = blockIdx.x * 128;
  const int n0 = blockIdx.y * 128;
  const int e  = blockIdx.z;
  const float* Wp = W2 + (size_t)e * DDIM * HDIM;
  const unsigned short* Ap = A + (size_t)e * T * DDIM;
  f32x4 acc[4][4];
#pragma unroll
  for (int i = 0; i < 4; ++i)
#pragma unroll
    for (int j = 0; j < 4; ++j) acc[i][j] = (f32x4)0.f;
  const int w = tid >> 6, lane = tid & 63;
  const int wm = w & 1, wn = w >> 1;
  const int r = lane & 15, q = lane >> 4;
  const int sa_m = tid >> 2, sa_c = tid & 3;
  const int sb_n = tid & 127, sb_k = tid >> 7;
  for (int kt = 0; kt < DDIM / 32; ++kt) {
    const int k0g = kt * 32;
#pragma unroll
    for (int it = 0; it < 2; ++it) {
      int m = sa_m + it * 64;
      bf16x8 v = *(const bf16x8*)(Ap + (size_t)(m0 + m) * DDIM + k0g + sa_c * 8);
      *(bf16x8*)(&lA[m * LDSS + sa_c * 8]) = v;
    }
    int col = n0 + sb_n;
    if (col > HDIM - 1) col = HDIM - 1;
#pragma unroll
    for (int it = 0; it < 2; ++it) {
      int k0 = (sb_k + it * 2) * 8;
      float f[8];
#pragma unroll
      for (int rr = 0; rr < 8; ++rr)
        f[rr] = Wp[(size_t)(k0g + k0 + rr) * HDIM + col];
      bf16x8 pv = { (short)f2bf(f[0]), (short)f2bf(f[1]), (short)f2bf(f[2]), (short)f2bf(f[3]),
                    (short)f2bf(f[4]), (short)f2bf(f[5]), (short)f2bf(f[6]), (short)f2bf(f[7]) };
      *(bf16x8*)(&lB[sb_n * LDSS + k0]) = pv;
    }
    __syncthreads();
    const unsigned short* pA = &lA[(wm * 64 + r) * LDSS + q * 8];
    const unsigned short* pB = &lB[(wn * 64 + r) * LDSS + q * 8];
    bf16x8 af[4], bfr[4];
#pragma unroll
    for (int i = 0; i < 4; ++i) af[i]  = *(const bf16x8*)(pA + i * 16 * LDSS);
#pragma unroll
    for (int j = 0; j < 4; ++j) bfr[j] = *(const bf16x8*)(pB + j * 16 * LDSS);
#pragma unroll
    for (int i = 0; i < 4; ++i)
#pragma unroll
      for (int j = 0; j < 4; ++j)
        acc[i][j] = __builtin_amdgcn_mfma_f32_16x16x32_bf16(af[i], bfr[j], acc[i][j], 0, 0, 0);
    __syncthreads();
  }
#pragma unroll
  for (int i = 0; i < 4; ++i) {
    const int mb = m0 + wm * 64 + i * 16 + q * 4;
#pragma unroll
    for (int j = 0; j < 4; ++j) {
      const int h = n0 + wn * 64 + j * 16 + r;
      if (h < HDIM) {
#pragma unroll
        for (int p = 0; p < 4; ++p)
          atomicAdd(&Y[(size_t)(mb + p) * HDIM + h], acc[i][j][p]);
      }
    }
  }
}

// ---------------------------------------------------------------------------
extern "C" void kernel_launch(void* const* d_in, const int* in_sizes, int n_in,
                              void* d_out, int out_size, void* d_ws, size_t ws_size,
                              hipStream_t stream) {
  const float* X  = (const float*)d_in[0];
  const float* RW = (const float*)d_in[1];
  const float* W1 = (const float*)d_in[2];
  const float* B1 = (const float*)d_in[3];
  const float* W2 = (const float*)d_in[4];
  const float* B2 = (const float*)d_in[5];
  float* Y = (float*)d_out;

  constexpr size_t XB_B  = (size_t)T * HDIM * 2;           //  5.9 MB bf16 X
  constexpr size_t AB_B  = (size_t)NE * T * DDIM * 2;      // 47.2 MB bf16 A'
  constexpr size_t W1T_B = (size_t)NE * TWO_D * HDIM * 2;  // 265.4 MB
  constexpr size_t W2T_B = (size_t)NE * HDIM * DDIM * 2;   // 132.7 MB
  constexpr size_t YP_B  = (size_t)NE * T * HDIM * 4;      // 94.4 MB fp32 partials
  constexpr size_t NEED  = XB_B + AB_B + W1T_B + W2T_B + YP_B;  // ~520 MiB

  if (ws_size >= NEED) {
    char* p = (char*)d_ws;
    unsigned short* Xb  = (unsigned short*)p; p += XB_B;
    unsigned short* Ab  = (unsigned short*)p; p += AB_B;
    unsigned short* W1T = (unsigned short*)p; p += W1T_B;
    unsigned short* W2T = (unsigned short*)p; p += W2T_B;
    float* Yp = (float*)p;

    hipLaunchKernelGGL(cvt_x_kernel, dim3((T * HDIM) / 2048), dim3(256), 0, stream, X, Xb);
    hipLaunchKernelGGL(transpose_cvt_kernel, dim3(TWO_D / 64, HDIM / 64, NE), dim3(256), 0, stream,
                       W1, W1T, HDIM, TWO_D);
    hipLaunchKernelGGL(transpose_cvt_kernel, dim3(HDIM / 64, DDIM / 64, NE), dim3(256), 0, stream,
                       W2, W2T, DDIM, HDIM);
    hipLaunchKernelGGL(gemm1_fast, dim3(T / 128, TWO_D / 128, NE), dim3(256), 0, stream,
                       Xb, W1T, B1, RW, Ab);
    hipLaunchKernelGGL(gemm2_fast, dim3(T / 128, (HDIM + 127) / 128, NE), dim3(256), 0, stream,
                       Ab, W2T, Yp);
    hipLaunchKernelGGL(reduce_bias_kernel, dim3((T * HDIM) / 1024), dim3(256), 0, stream,
                       Yp, RW, B2, Y);
  } else {
    unsigned short* Abuf = (unsigned short*)d_ws;
    hipLaunchKernelGGL(init_bias_kernel, dim3(45, 1024), dim3(64), 0, stream, RW, B2, Y);
    hipLaunchKernelGGL(gemm1_act_kernel, dim3(8, 45, 8), dim3(256), 0, stream, X, W1, B1, RW, Abuf);
    hipLaunchKernelGGL(gemm2_acc_kernel, dim3(8, 23, 8), dim3(256), 0, stream, Abuf, W2, Y);
  }
}

// Round 2
// 1492.913 us; speedup vs baseline: 1.1323x; 1.0420x over previous
//
#include <hip/hip_runtime.h>

namespace {

constexpr int T     = 1024;
constexpr int HDIM  = 2880;
constexpr int DDIM  = 2880;
constexpr int NE    = 8;
constexpr int TWO_D = 5760;
constexpr float ALPHA = 1.702f;
constexpr float LIMIT = 7.0f;

// fallback-path LDS row stride
constexpr int LDSS = 40;

typedef __attribute__((ext_vector_type(8))) short bf16x8;          // MFMA A/B frag (4 VGPR)
typedef __attribute__((ext_vector_type(4))) unsigned short u16x4;  // 8B LDS store
typedef __attribute__((ext_vector_type(4))) float f32x4;           // MFMA C/D frag
typedef __attribute__((ext_vector_type(4))) unsigned u32x4;

__device__ __forceinline__ unsigned short f2bf(float f) {
  union { float f; unsigned u; } x; x.f = f;
  unsigned u = x.u;
  u += 0x7fffu + ((u >> 16) & 1u);   // RNE
  return (unsigned short)(u >> 16);
}

// async global->LDS, 16B per lane. LDS dest = wave-uniform base + lane*16.
__device__ __forceinline__ void async16(const void* g, void* l) {
  __builtin_amdgcn_global_load_lds(
      (const __attribute__((address_space(1))) unsigned int*)g,
      (__attribute__((address_space(3))) unsigned int*)l, 16, 0, 0);
}

} // namespace

// ===========================================================================
// FAST PATH
// ===========================================================================

// X fp32 -> bf16, streaming. grid T*H/2048, block 256.
__global__ __launch_bounds__(256) void cvt_x_kernel(const float* __restrict__ X,
                                                    unsigned short* __restrict__ Xb) {
  const int i = (blockIdx.x * 256 + threadIdx.x) * 8;
  const f32x4 a = *(const f32x4*)(X + i);
  const f32x4 b = *(const f32x4*)(X + i + 4);
  bf16x8 pv;
  pv[0] = (short)f2bf(a.x); pv[1] = (short)f2bf(a.y);
  pv[2] = (short)f2bf(a.z); pv[3] = (short)f2bf(a.w);
  pv[4] = (short)f2bf(b.x); pv[5] = (short)f2bf(b.y);
  pv[6] = (short)f2bf(b.z); pv[7] = (short)f2bf(b.w);
  *(bf16x8*)(Xb + i) = pv;
}

// src (gridDim.z, R, C) fp32  ->  dst (gridDim.z, C, R) bf16.  64x64 tile.
// Row-pair packing: lt32[c][r2] = bf(src[2r2][c]) | bf(src[2r2+1][c])<<16.
// Phase-1 writes 2-way-free (33-word rows); phase-2: 8 conflict-free b32 reads,
// 32 B/lane contiguous global stores (4 lanes = 128 B per dst row).
__global__ __launch_bounds__(256) void transpose_cvt_kernel(
    const float* __restrict__ src, unsigned short* __restrict__ dst,
    int R, int C) {
  __shared__ unsigned lt32[64][33];
  const size_t eo = (size_t)blockIdx.z * R * C;
  const float* sp = src + eo;
  unsigned short* dp = dst + eo;
  const int c0 = blockIdx.x * 64;
  const int r0 = blockIdx.y * 64;
  const int t  = threadIdx.x;

  {
    const int r2 = t >> 3;          // 0..31 row-pair
    const int cb = (t & 7) * 8;     // col base
    const float* p0 = sp + (size_t)(r0 + 2 * r2) * C + c0 + cb;
    const f32x4 a0 = *(const f32x4*)(p0);
    const f32x4 a1 = *(const f32x4*)(p0 + 4);
    const f32x4 b0 = *(const f32x4*)(p0 + C);
    const f32x4 b1 = *(const f32x4*)(p0 + C + 4);
    unsigned wv[8];
    wv[0] = (unsigned)f2bf(a0.x) | ((unsigned)f2bf(b0.x) << 16);
    wv[1] = (unsigned)f2bf(a0.y) | ((unsigned)f2bf(b0.y) << 16);
    wv[2] = (unsigned)f2bf(a0.z) | ((unsigned)f2bf(b0.z) << 16);
    wv[3] = (unsigned)f2bf(a0.w) | ((unsigned)f2bf(b0.w) << 16);
    wv[4] = (unsigned)f2bf(a1.x) | ((unsigned)f2bf(b1.x) << 16);
    wv[5] = (unsigned)f2bf(a1.y) | ((unsigned)f2bf(b1.y) << 16);
    wv[6] = (unsigned)f2bf(a1.z) | ((unsigned)f2bf(b1.z) << 16);
    wv[7] = (unsigned)f2bf(a1.w) | ((unsigned)f2bf(b1.w) << 16);
#pragma unroll
    for (int j = 0; j < 8; ++j) lt32[cb + j][r2] = wv[j];
  }
  __syncthreads();
  {
    const int c  = t >> 2;          // 0..63 dst row (src col)
    const int rs = (t & 3) * 8;     // row-pair base
    unsigned o[8];
#pragma unroll
    for (int j = 0; j < 8; ++j) o[j] = lt32[c][rs + j];
    unsigned short* q = dp + (size_t)(c0 + c) * R + r0 + 2 * rs;
    u32x4 v0 = { o[0], o[1], o[2], o[3] };
    u32x4 v1 = { o[4], o[5], o[6], o[7] };
    *(u32x4*)(q)     = v0;
    *(u32x4*)(q + 8) = v1;
  }
}

// GEMM1 (m97 structure): A' = act(X @ W1 + b1) * rw  -> (E,T,D) bf16.
// XCD-chunked swizzle: each XCD owns one expert; m fastest within XCD so the
// 8 m-blocks sharing a 737 KB W1T slice hit the same L2.
// grid (8,45,8), block 256.
__global__ __launch_bounds__(256) void gemm1_fast(
    const unsigned short* __restrict__ Xb,   // (T,H) bf16
    const unsigned short* __restrict__ W1T,  // (E,2D,H) bf16  (pre-transposed)
    const float* __restrict__ B1,
    const float* __restrict__ RW,
    unsigned short* __restrict__ A)          // (E,T,D) bf16
{
  __shared__ __align__(16) unsigned short lA[128 * 32];
  __shared__ __align__(16) unsigned short lB[128 * 32];

  const int tid = threadIdx.x;
  // nwg = 2880 = 8*360; lid walks m fastest; XCD k gets lids [360k, 360k+360)
  const int bid = blockIdx.x + (blockIdx.y << 3) + blockIdx.z * 360;
  const int lid = (bid & 7) * 360 + (bid >> 3);
  const int m0 = (lid & 7) * 128;
  const int n0 = ((lid >> 3) % 45) * 128;
  const int e  = lid / 360;
  const unsigned short* Wp = W1T + (size_t)e * TWO_D * HDIM;

  f32x4 acc[4][4];
#pragma unroll
  for (int i = 0; i < 4; ++i)
#pragma unroll
    for (int j = 0; j < 4; ++j) acc[i][j] = (f32x4)0.f;

  const int w    = tid >> 6;
  const int lane = tid & 63;
  const int wm   = w & 1, wn = w >> 1;
  const int r    = lane & 15, q = lane >> 4;

  const int srow = lane >> 2;
  const int skc  = (lane & 3) * 8;
  const unsigned short* ga = Xb + (size_t)(m0 + w * 32 + srow) * HDIM + skc;
  const unsigned short* gb = Wp + (size_t)(n0 + w * 32 + srow) * HDIM + skc;
  unsigned short* la0 = lA + (w * 2) * 512;   // wave-uniform LDS bases
  unsigned short* lb0 = lB + (w * 2) * 512;

  for (int kt = 0; kt < HDIM / 32; ++kt) {
    const int k0 = kt * 32;
    async16(ga + k0,                        la0);
    async16(ga + (size_t)16 * HDIM + k0,    la0 + 512);
    async16(gb + k0,                        lb0);
    async16(gb + (size_t)16 * HDIM + k0,    lb0 + 512);
    __syncthreads();

    const unsigned short* pA = &lA[(wm * 64 + r) * 32 + q * 8];
    const unsigned short* pB = &lB[(wn * 64 + r) * 32 + q * 8];
    bf16x8 af[4], bfr[4];
#pragma unroll
    for (int i = 0; i < 4; ++i) af[i]  = *(const bf16x8*)(pA + i * 512);
#pragma unroll
    for (int j = 0; j < 4; ++j) bfr[j] = *(const bf16x8*)(pB + j * 512);
#pragma unroll
    for (int i = 0; i < 4; ++i)
#pragma unroll
      for (int j = 0; j < 4; ++j)
        acc[i][j] = __builtin_amdgcn_mfma_f32_16x16x32_bf16(af[i], bfr[j], acc[i][j], 0, 0, 0);

    __syncthreads();
  }

  // epilogue: bias, gate/up pairing via shfl_xor(1), activation, rw scale
  const float* bp = B1 + (size_t)e * TWO_D;
#pragma unroll
  for (int i = 0; i < 4; ++i) {
    const int mb = m0 + wm * 64 + i * 16 + q * 4;
    float rwv[4];
#pragma unroll
    for (int p = 0; p < 4; ++p) rwv[p] = RW[(mb + p) * NE + e];
#pragma unroll
    for (int j = 0; j < 4; ++j) {
      const int c = n0 + wn * 64 + j * 16 + r;
      const float bias = bp[c];
#pragma unroll
      for (int p = 0; p < 4; ++p) {
        float v = acc[i][j][p] + bias;
        float o = __shfl_xor(v, 1, 64);
        float gate = (r & 1) ? o : v;
        float up   = (r & 1) ? v : o;
        gate = fminf(gate, LIMIT);
        up   = fminf(fmaxf(up, -LIMIT), LIMIT);
        float glu = gate / (1.f + __expf(-ALPHA * gate));
        float a   = (up + 1.f) * glu * rwv[p];
        if ((r & 1) == 0) {
          int d = c >> 1;
          A[(size_t)e * T * DDIM + (size_t)(mb + p) * DDIM + d] = f2bf(a);
        }
      }
    }
  }
}

// GEMM2 (m97 structure): Yp[e] = A'[e] @ W2T[e]^T, per-expert partials.
// Same XCD-chunked swizzle (nwg = 1472 = 8*184). grid (8,23,8), block 256.
__global__ __launch_bounds__(256) void gemm2_fast(
    const unsigned short* __restrict__ A,    // (E,T,D) bf16
    const unsigned short* __restrict__ W2T,  // (E,H,D) bf16 (pre-transposed)
    float* __restrict__ Yp)                  // (E,T,H) fp32 partials
{
  __shared__ __align__(16) unsigned short lA[128 * 32];
  __shared__ __align__(16) unsigned short lB[128 * 32];

  const int tid = threadIdx.x;
  const int bid = blockIdx.x + (blockIdx.y << 3) + blockIdx.z * 184;
  const int lid = (bid & 7) * 184 + (bid >> 3);
  const int m0 = (lid & 7) * 128;
  const int n0 = ((lid >> 3) % 23) * 128;
  const int e  = lid / 184;
  const unsigned short* Ap = A   + (size_t)e * T * DDIM;
  const unsigned short* Wp = W2T + (size_t)e * HDIM * DDIM;

  f32x4 acc[4][4];
#pragma unroll
  for (int i = 0; i < 4; ++i)
#pragma unroll
    for (int j = 0; j < 4; ++j) acc[i][j] = (f32x4)0.f;

  const int w    = tid >> 6;
  const int lane = tid & 63;
  const int wm   = w & 1, wn = w >> 1;
  const int r    = lane & 15, q = lane >> 4;

  const int srow = lane >> 2;
  const int skc  = (lane & 3) * 8;
  int br0 = n0 + w * 32 + srow;       // B rows (h), clamp ragged tail
  int br1 = br0 + 16;
  if (br0 > HDIM - 1) br0 = HDIM - 1;
  if (br1 > HDIM - 1) br1 = HDIM - 1;
  const unsigned short* ga  = Ap + (size_t)(m0 + w * 32 + srow) * DDIM + skc;
  const unsigned short* gb0 = Wp + (size_t)br0 * DDIM + skc;
  const unsigned short* gb1 = Wp + (size_t)br1 * DDIM + skc;
  unsigned short* la0 = lA + (w * 2) * 512;
  unsigned short* lb0 = lB + (w * 2) * 512;

  for (int kt = 0; kt < DDIM / 32; ++kt) {
    const int k0 = kt * 32;
    async16(ga  + k0,                     la0);
    async16(ga  + (size_t)16 * DDIM + k0, la0 + 512);
    async16(gb0 + k0,                     lb0);
    async16(gb1 + k0,                     lb0 + 512);
    __syncthreads();

    const unsigned short* pA = &lA[(wm * 64 + r) * 32 + q * 8];
    const unsigned short* pB = &lB[(wn * 64 + r) * 32 + q * 8];
    bf16x8 af[4], bfr[4];
#pragma unroll
    for (int i = 0; i < 4; ++i) af[i]  = *(const bf16x8*)(pA + i * 512);
#pragma unroll
    for (int j = 0; j < 4; ++j) bfr[j] = *(const bf16x8*)(pB + j * 512);
#pragma unroll
    for (int i = 0; i < 4; ++i)
#pragma unroll
      for (int j = 0; j < 4; ++j)
        acc[i][j] = __builtin_amdgcn_mfma_f32_16x16x32_bf16(af[i], bfr[j], acc[i][j], 0, 0, 0);

    __syncthreads();
  }

#pragma unroll
  for (int i = 0; i < 4; ++i) {
    const int mb = m0 + wm * 64 + i * 16 + q * 4;
#pragma unroll
    for (int j = 0; j < 4; ++j) {
      const int h = n0 + wn * 64 + j * 16 + r;
      if (h < HDIM) {
#pragma unroll
        for (int p = 0; p < 4; ++p)
          Yp[((size_t)e * T + (mb + p)) * HDIM + h] = acc[i][j][p];
      }
    }
  }
}

// Y[t,h] = sum_e Yp[e,t,h] + sum_e rw[t,e]*b2[e,h].  grid T*H/1024, block 256.
__global__ __launch_bounds__(256) void reduce_bias_kernel(
    const float* __restrict__ Yp, const float* __restrict__ RW,
    const float* __restrict__ B2, float* __restrict__ Y) {
  const int idx = (blockIdx.x * 256 + threadIdx.x) * 4;
  const int t = idx / HDIM;
  const int h = idx - t * HDIM;
  f32x4 s = (f32x4)0.f;
#pragma unroll
  for (int e = 0; e < NE; ++e) {
    const f32x4 v = *(const f32x4*)(Yp + ((size_t)e * T + t) * HDIM + h);
    const f32x4 b = *(const f32x4*)(B2 + (size_t)e * HDIM + h);
    const float rw = RW[t * NE + e];
    s.x += v.x + rw * b.x;
    s.y += v.y + rw * b.y;
    s.z += v.z + rw * b.z;
    s.w += v.w + rw * b.w;
  }
  *(f32x4*)(Y + idx) = s;
}

// ===========================================================================
// FALLBACK PATH (previous verified kernels, used if workspace too small)
// ===========================================================================

__global__ void init_bias_kernel(const float* __restrict__ RW,
                                 const float* __restrict__ B2,
                                 float* __restrict__ Y) {
  int h = blockIdx.x * 64 + threadIdx.x;
  int t = blockIdx.y;
  float s = 0.f;
#pragma unroll
  for (int e = 0; e < NE; ++e) s += RW[t * NE + e] * B2[e * HDIM + h];
  Y[(size_t)t * HDIM + h] = s;
}

__global__ __launch_bounds__(256) void gemm1_act_kernel(
    const float* __restrict__ X, const float* __restrict__ W1,
    const float* __restrict__ B1, const float* __restrict__ RW,
    unsigned short* __restrict__ A) {
  __shared__ __align__(16) unsigned short lA[128 * LDSS];
  __shared__ __align__(16) unsigned short lB[128 * LDSS];
  const int tid = threadIdx.x;
  const int m0 = blockIdx.x * 128;
  const int n0 = blockIdx.y * 128;
  const int e  = blockIdx.z;
  const float* Wp = W1 + (size_t)e * HDIM * TWO_D;
  f32x4 acc[4][4];
#pragma unroll
  for (int i = 0; i < 4; ++i)
#pragma unroll
    for (int j = 0; j < 4; ++j) acc[i][j] = (f32x4)0.f;
  const int w = tid >> 6, lane = tid & 63;
  const int wm = w & 1, wn = w >> 1;
  const int r = lane & 15, q = lane >> 4;
  const int sa_m = tid >> 3, sa_q = tid & 7;
  const int sb_n = tid & 127, sb_k = tid >> 7;
  for (int kt = 0; kt < HDIM / 32; ++kt) {
    const int k0g = kt * 32;
#pragma unroll
    for (int it = 0; it < 4; ++it) {
      int m = sa_m + it * 32;
      const f32x4 v = *(const f32x4*)(X + (size_t)(m0 + m) * HDIM + k0g + sa_q * 4);
      u16x4 pv = { f2bf(v.x), f2bf(v.y), f2bf(v.z), f2bf(v.w) };
      *(u16x4*)(&lA[m * LDSS + sa_q * 4]) = pv;
    }
#pragma unroll
    for (int it = 0; it < 2; ++it) {
      int k0 = (sb_k + it * 2) * 8;
      float f[8];
#pragma unroll
      for (int rr = 0; rr < 8; ++rr)
        f[rr] = Wp[(size_t)(k0g + k0 + rr) * TWO_D + n0 + sb_n];
      bf16x8 pv = { (short)f2bf(f[0]), (short)f2bf(f[1]), (short)f2bf(f[2]), (short)f2bf(f[3]),
                    (short)f2bf(f[4]), (short)f2bf(f[5]), (short)f2bf(f[6]), (short)f2bf(f[7]) };
      *(bf16x8*)(&lB[sb_n * LDSS + k0]) = pv;
    }
    __syncthreads();
    const unsigned short* pA = &lA[(wm * 64 + r) * LDSS + q * 8];
    const unsigned short* pB = &lB[(wn * 64 + r) * LDSS + q * 8];
    bf16x8 af[4], bfr[4];
#pragma unroll
    for (int i = 0; i < 4; ++i) af[i]  = *(const bf16x8*)(pA + i * 16 * LDSS);
#pragma unroll
    for (int j = 0; j < 4; ++j) bfr[j] = *(const bf16x8*)(pB + j * 16 * LDSS);
#pragma unroll
    for (int i = 0; i < 4; ++i)
#pragma unroll
      for (int j = 0; j < 4; ++j)
        acc[i][j] = __builtin_amdgcn_mfma_f32_16x16x32_bf16(af[i], bfr[j], acc[i][j], 0, 0, 0);
    __syncthreads();
  }
  const float* bp = B1 + (size_t)e * TWO_D;
#pragma unroll
  for (int i = 0; i < 4; ++i) {
    const int mb = m0 + wm * 64 + i * 16 + q * 4;
    float rwv[4];
#pragma unroll
    for (int p = 0; p < 4; ++p) rwv[p] = RW[(mb + p) * NE + e];
#pragma unroll
    for (int j = 0; j < 4; ++j) {
      const int c = n0 + wn * 64 + j * 16 + r;
      const float bias = bp[c];
#pragma unroll
      for (int p = 0; p < 4; ++p) {
        float v = acc[i][j][p] + bias;
        float o = __shfl_xor(v, 1, 64);
        float gate = (r & 1) ? o : v;
        float up   = (r & 1) ? v : o;
        gate = fminf(gate, LIMIT);
        up   = fminf(fmaxf(up, -LIMIT), LIMIT);
        float glu = gate / (1.f + __expf(-ALPHA * gate));
        float a   = (up + 1.f) * glu * rwv[p];
        if ((r & 1) == 0) {
          int d = c >> 1;
          A[(size_t)e * T * DDIM + (size_t)(mb + p) * DDIM + d] = f2bf(a);
        }
      }
    }
  }
}

__global__ __launch_bounds__(256) void gemm2_acc_kernel(
    const unsigned short* __restrict__ A, const float* __restrict__ W2,
    float* __restrict__ Y) {
  __shared__ __align__(16) unsigned short lA[128 * LDSS];
  __shared__ __align__(16) unsigned short lB[128 * LDSS];
  const int tid = threadIdx.x;
  const int m0 = blockIdx.x * 128;
  const int n0 = blockIdx.y * 128;
  const int e  = blockIdx.z;
  const float* Wp = W2 + (size_t)e * DDIM * HDIM;
  const unsigned short* Ap = A + (size_t)e * T * DDIM;
  f32x4 acc[4][4];
#pragma unroll
  for (int i = 0; i < 4; ++i)
#pragma unroll
    for (int j = 0; j < 4; ++j) acc[i][j] = (f32x4)0.f;
  const int w = tid >> 6, lane = tid & 63;
  const int wm = w & 1, wn = w >> 1;
  const int r = lane & 15, q = lane >> 4;
  const int sa_m = tid >> 2, sa_c = tid & 3;
  const int sb_n = tid & 127, sb_k = tid >> 7;
  for (int kt = 0; kt < DDIM / 32; ++kt) {
    const int k0g = kt * 32;
#pragma unroll
    for (int it = 0; it < 2; ++it) {
      int m = sa_m + it * 64;
      bf16x8 v = *(const bf16x8*)(Ap + (size_t)(m0 + m) * DDIM + k0g + sa_c * 8);
      *(bf16x8*)(&lA[m * LDSS + sa_c * 8]) = v;
    }
    int col = n0 + sb_n;
    if (col > HDIM - 1) col = HDIM - 1;
#pragma unroll
    for (int it = 0; it < 2; ++it) {
      int k0 = (sb_k + it * 2) * 8;
      float f[8];
#pragma unroll
      for (int rr = 0; rr < 8; ++rr)
        f[rr] = Wp[(size_t)(k0g + k0 + rr) * HDIM + col];
      bf16x8 pv = { (short)f2bf(f[0]), (short)f2bf(f[1]), (short)f2bf(f[2]), (short)f2bf(f[3]),
                    (short)f2bf(f[4]), (short)f2bf(f[5]), (short)f2bf(f[6]), (short)f2bf(f[7]) };
      *(bf16x8*)(&lB[sb_n * LDSS + k0]) = pv;
    }
    __syncthreads();
    const unsigned short* pA = &lA[(wm * 64 + r) * LDSS + q * 8];
    const unsigned short* pB = &lB[(wn * 64 + r) * LDSS + q * 8];
    bf16x8 af[4], bfr[4];
#pragma unroll
    for (int i = 0; i < 4; ++i) af[i]  = *(const bf16x8*)(pA + i * 16 * LDSS);
#pragma unroll
    for (int j = 0; j < 4; ++j) bfr[j] = *(const bf16x8*)(pB + j * 16 * LDSS);
#pragma unroll
    for (int i = 0; i < 4; ++i)
#pragma unroll
      for (int j = 0; j < 4; ++j)
        acc[i][j] = __builtin_amdgcn_mfma_f32_16x16x32_bf16(af[i], bfr[j], acc[i][j], 0, 0, 0);
    __syncthreads();
  }
#pragma unroll
  for (int i = 0; i < 4; ++i) {
    const int mb = m0 + wm * 64 + i * 16 + q * 4;
#pragma unroll
    for (int j = 0; j < 4; ++j) {
      const int h = n0 + wn * 64 + j * 16 + r;
      if (h < HDIM) {
#pragma unroll
        for (int p = 0; p < 4; ++p)
          atomicAdd(&Y[(size_t)(mb + p) * HDIM + h], acc[i][j][p]);
      }
    }
  }
}

// ---------------------------------------------------------------------------
extern "C" void kernel_launch(void* const* d_in, const int* in_sizes, int n_in,
                              void* d_out, int out_size, void* d_ws, size_t ws_size,
                              hipStream_t stream) {
  const float* X  = (const float*)d_in[0];
  const float* RW = (const float*)d_in[1];
  const float* W1 = (const float*)d_in[2];
  const float* B1 = (const float*)d_in[3];
  const float* W2 = (const float*)d_in[4];
  const float* B2 = (const float*)d_in[5];
  float* Y = (float*)d_out;

  constexpr size_t XB_B  = (size_t)T * HDIM * 2;           //  5.9 MB bf16 X
  constexpr size_t AB_B  = (size_t)NE * T * DDIM * 2;      // 47.2 MB bf16 A'
  constexpr size_t W1T_B = (size_t)NE * TWO_D * HDIM * 2;  // 265.4 MB
  constexpr size_t W2T_B = (size_t)NE * HDIM * DDIM * 2;   // 132.7 MB
  constexpr size_t YP_B  = (size_t)NE * T * HDIM * 4;      // 94.4 MB fp32 partials
  constexpr size_t NEED  = XB_B + AB_B + W1T_B + W2T_B + YP_B;  // ~520 MiB

  if (ws_size >= NEED) {
    char* p = (char*)d_ws;
    unsigned short* Xb  = (unsigned short*)p; p += XB_B;
    unsigned short* Ab  = (unsigned short*)p; p += AB_B;
    unsigned short* W1T = (unsigned short*)p; p += W1T_B;
    unsigned short* W2T = (unsigned short*)p; p += W2T_B;
    float* Yp = (float*)p;

    hipLaunchKernelGGL(cvt_x_kernel, dim3((T * HDIM) / 2048), dim3(256), 0, stream, X, Xb);
    hipLaunchKernelGGL(transpose_cvt_kernel, dim3(TWO_D / 64, HDIM / 64, NE), dim3(256), 0, stream,
                       W1, W1T, HDIM, TWO_D);
    hipLaunchKernelGGL(transpose_cvt_kernel, dim3(HDIM / 64, DDIM / 64, NE), dim3(256), 0, stream,
                       W2, W2T, DDIM, HDIM);
    hipLaunchKernelGGL(gemm1_fast, dim3(T / 128, TWO_D / 128, NE), dim3(256), 0, stream,
                       Xb, W1T, B1, RW, Ab);
    hipLaunchKernelGGL(gemm2_fast, dim3(T / 128, (HDIM + 127) / 128, NE), dim3(256), 0, stream,
                       Ab, W2T, Yp);
    hipLaunchKernelGGL(reduce_bias_kernel, dim3((T * HDIM) / 1024), dim3(256), 0, stream,
                       Yp, RW, B2, Y);
  } else {
    unsigned short* Abuf = (unsigned short*)d_ws;
    hipLaunchKernelGGL(init_bias_kernel, dim3(45, 1024), dim3(64), 0, stream, RW, B2, Y);
    hipLaunchKernelGGL(gemm1_act_kernel, dim3(8, 45, 8), dim3(256), 0, stream, X, W1, B1, RW, Abuf);
    hipLaunchKernelGGL(gemm2_acc_kernel, dim3(8, 23, 8), dim3(256), 0, stream, Abuf, W2, Y);
  }
}